// Round 5
// baseline (229.514 us; speedup 1.0000x reference)
//
#include <hip/hip_runtime.h>

#define NBINS 256
#define NCH 3
#define NHIST (2 * NCH * NBINS)    // 1536 global bins (input + label)
#define HW4 65536                   // 512*512/4 float4s per (batch,channel) plane
#define THREADS 256
#define BLOCKS_PER_JOB 512
#define STEP (2 * NCH * HW4)        // float4 stride between a thread's batches

// ===========================================================================
// A/B round. Model H: scattered-address LDS wave-ops cost ~30 cyc (RMW pair
// = 2 lane-ops/element -> 184K cyc/CU = 77us for full data), atomics ~75 under
// R1's contention. hist_atomic tests whether ds_add with pair-private hists +
// benign banking gets the ~30-40 cyc cost (1 op/element -> 2x win) or is
// intrinsically ~75 (R1 redux). Each kernel handles ONE array (half data);
// same stream => sequential => clean per-dispatch A/B timing.
// ===========================================================================

// ---------------------------------------------------------------------------
// A: pair-shared u8x4 histograms + ds_add_u32 (fire-and-forget, no waits).
// Layout: word = wave*2048 + pair*64 + grp, pair = lane>>1, grp = bin>>2.
// Max per-u8 count = 2 thr * 16 float4 * 4 = 128 < 255 (any input). 32 KB.
// ---------------------------------------------------------------------------
__global__ __launch_bounds__(THREADS) void hist_atomic(
    const float* __restrict__ src, unsigned int* __restrict__ gh) {
    __shared__ unsigned int sh[8192];  // 4 waves * 32 pairs * 64 words
    const int tid  = threadIdx.x;
    const int wave = tid >> 6;
    const int lane = tid & 63;
    const int pair = lane >> 1;

    uint4* shv = (uint4*)sh;
    #pragma unroll
    for (int i = 0; i < 8; ++i)
        shv[tid + i * THREADS] = make_uint4(0u, 0u, 0u, 0u);
    __syncthreads();

    const int ch  = blockIdx.x / BLOCKS_PER_JOB;   // 0..2
    const int bij = blockIdx.x % BLOCKS_PER_JOB;

    const float4* __restrict__ src4 = (const float4*)src;
    unsigned int* const base = &sh[wave * 2048 + pair * 64];

    const unsigned tg  = ((unsigned)bij << 8) | (unsigned)tid;  // 0..131071
    const unsigned hi  = tg >> 16;                               // 0 or 1
    const unsigned pos = tg & (HW4 - 1);
    const unsigned base_idx = hi * (NCH * HW4) + (unsigned)ch * HW4 + pos;

    #define ATOM1(x) do { \
        const int _b = (int)fminf(fmaxf((x), 0.f), 255.f); \
        atomicAdd(&base[_b >> 2], 1u << ((_b & 3) << 3)); } while (0)
    #define ATOM4(v) do { ATOM1((v).x); ATOM1((v).y); ATOM1((v).z); ATOM1((v).w); } while (0)

    float4 c0 = src4[base_idx + 0u * STEP];
    float4 c1 = src4[base_idx + 1u * STEP];
    float4 c2 = src4[base_idx + 2u * STEP];
    float4 c3 = src4[base_idx + 3u * STEP];
    #pragma unroll
    for (int g2 = 0; g2 < 4; ++g2) {
        float4 n0, n1, n2, n3;
        if (g2 < 3) {
            const unsigned k = (unsigned)(4 * g2 + 4);
            n0 = src4[base_idx + (k + 0u) * STEP];
            n1 = src4[base_idx + (k + 1u) * STEP];
            n2 = src4[base_idx + (k + 2u) * STEP];
            n3 = src4[base_idx + (k + 3u) * STEP];
        }
        ATOM4(c0); ATOM4(c1); ATOM4(c2); ATOM4(c3);
        if (g2 < 3) { c0 = n0; c1 = n1; c2 = n2; c3 = n3; }
    }
    __syncthreads();

    // Flush phase 1: wave-local. Lane l sums grp l over 32 pairs, u16x2 packed
    // (max 32*128 = 4096 < 65535). Reads word pp*64 + l -> bank l%32, clean.
    {
        const unsigned int* rb = &sh[wave * 2048];
        unsigned lo = 0u, hiS = 0u;
        #pragma unroll
        for (int p = 0; p < 32; ++p) {
            const int pp = (p + lane) & 31;
            const unsigned v = rb[pp * 64 + lane];
            lo  += v & 0x00FF00FFu;
            hiS += (v >> 8) & 0x00FF00FFu;
        }
        sh[wave * 2048 + lane]      = lo;   // reads above precede (in-order)
        sh[wave * 2048 + 64 + lane] = hiS;
    }
    __syncthreads();

    // Flush phase 2: thread t owns bin t; combine the 4 wave regions.
    {
        const int grp = tid >> 2, byte = tid & 3;
        const int off = (byte & 1) ? 64 : 0;
        unsigned s = 0u;
        #pragma unroll
        for (int q = 0; q < 4; ++q) {
            const unsigned v = sh[q * 2048 + off + grp];
            s += (byte & 2) ? (v >> 16) : (v & 0xFFFFu);
        }
        atomicAdd(&gh[ch * NBINS + tid], s);   // arr = 0 (input)
    }
}

// ---------------------------------------------------------------------------
// B: round-3 verified per-thread RMW (batched reads, dedup, 64 KB, 0 confl).
// ---------------------------------------------------------------------------
__device__ __forceinline__ void batch4(unsigned int* lbase, float4 v) {
    const int b0 = (int)fminf(fmaxf(v.x, 0.f), 255.f);
    const int b1 = (int)fminf(fmaxf(v.y, 0.f), 255.f);
    const int b2 = (int)fminf(fmaxf(v.z, 0.f), 255.f);
    const int b3 = (int)fminf(fmaxf(v.w, 0.f), 255.f);
    const int w0 = b0 >> 2, w1 = b1 >> 2, w2 = b2 >> 2, w3 = b3 >> 2;
    unsigned int i0 = 1u << ((b0 & 3) << 3);
    unsigned int i1 = 1u << ((b1 & 3) << 3);
    unsigned int i2 = 1u << ((b2 & 3) << 3);
    unsigned int i3 = 1u << ((b3 & 3) << 3);
    unsigned int* const p0 = lbase + w0 * 64;
    unsigned int* const p1 = lbase + w1 * 64;
    unsigned int* const p2 = lbase + w2 * 64;
    unsigned int* const p3 = lbase + w3 * 64;
    const unsigned int r0 = *p0;
    const unsigned int r1 = *p1;
    const unsigned int r2 = *p2;
    const unsigned int r3 = *p3;
    if (w0 == w1) { i1 += i0; i0 = 0; }
    if (w0 == w2) { i2 += i0; i0 = 0; }
    if (w0 == w3) { i3 += i0; i0 = 0; }
    if (w1 == w2) { i2 += i1; i1 = 0; }
    if (w1 == w3) { i3 += i1; i1 = 0; }
    if (w2 == w3) { i3 += i2; i2 = 0; }
    *p0 = r0 + i0;
    *p1 = r1 + i1;
    *p2 = r2 + i2;
    *p3 = r3 + i3;
}

__global__ __launch_bounds__(THREADS) void hist_rmw(
    const float* __restrict__ src, unsigned int* __restrict__ gh) {
    __shared__ unsigned int sh[16384];  // 64 KB: per-thread 64-word u8x4 hists
    const int tid  = threadIdx.x;
    const int wave = tid >> 6;
    const int lane = tid & 63;

    uint4* shv = (uint4*)sh;
    #pragma unroll
    for (int i = 0; i < 16; ++i)
        shv[tid + i * THREADS] = make_uint4(0u, 0u, 0u, 0u);
    __syncthreads();

    const int ch  = blockIdx.x / BLOCKS_PER_JOB;   // 0..2
    const int bij = blockIdx.x % BLOCKS_PER_JOB;

    const float4* __restrict__ src4 = (const float4*)src;
    unsigned int* const lbase = &sh[wave * 4096 + lane];

    const unsigned tg  = ((unsigned)bij << 8) | (unsigned)tid;
    const unsigned hi  = tg >> 16;
    const unsigned pos = tg & (HW4 - 1);
    const unsigned base_idx = hi * (NCH * HW4) + (unsigned)ch * HW4 + pos;

    float4 c0 = src4[base_idx + 0u * STEP];
    float4 c1 = src4[base_idx + 1u * STEP];
    float4 c2 = src4[base_idx + 2u * STEP];
    float4 c3 = src4[base_idx + 3u * STEP];
    #pragma unroll
    for (int g2 = 0; g2 < 4; ++g2) {
        float4 n0, n1, n2, n3;
        if (g2 < 3) {
            const unsigned k = (unsigned)(4 * g2 + 4);
            n0 = src4[base_idx + (k + 0u) * STEP];
            n1 = src4[base_idx + (k + 1u) * STEP];
            n2 = src4[base_idx + (k + 2u) * STEP];
            n3 = src4[base_idx + (k + 3u) * STEP];
        }
        batch4(lbase, c0);
        batch4(lbase, c1);
        batch4(lbase, c2);
        batch4(lbase, c3);
        if (g2 < 3) { c0 = n0; c1 = n1; c2 = n2; c3 = n3; }
    }
    __syncthreads();

    // Flush: thread t owns bin t; sum its byte over 4 waves x 64 lanes.
    unsigned int sum = 0;
    const int grp = tid >> 2;
    const int sh8 = (tid & 3) << 3;
    #pragma unroll
    for (int w = 0; w < 4; ++w) {
        const unsigned int* base = &sh[w * 4096 + grp * 64];
        #pragma unroll
        for (int c = 0; c < 16; ++c) {
            const int cc = (c + tid) & 15;
            const uint4 q = *(const uint4*)(base + cc * 4);
            sum += ((q.x >> sh8) & 0xFFu) + ((q.y >> sh8) & 0xFFu)
                 + ((q.z >> sh8) & 0xFFu) + ((q.w >> sh8) & 0xFFu);
        }
    }
    atomicAdd(&gh[(NCH + ch) * NBINS + tid], sum);   // arr = 1 (label)
}

// ---------------------------------------------------------------------------
// Final Bhattacharyya kernel: 1 block x 256 threads, fp64 reduction.
// ---------------------------------------------------------------------------
__device__ __forceinline__ double block_reduce256(double v, double* sh4) {
    const int t = threadIdx.x;
    const int lane = t & 63, w = t >> 6;
    #pragma unroll
    for (int o = 32; o > 0; o >>= 1) v += __shfl_down(v, o, 64);
    if (lane == 0) sh4[w] = v;
    __syncthreads();
    double r = sh4[0] + sh4[1] + sh4[2] + sh4[3];
    __syncthreads();
    return r;
}

__global__ __launch_bounds__(256) void bhat_kernel(
    const unsigned int* __restrict__ gh, float* __restrict__ out) {
    __shared__ double sh4[4];
    const int t = threadIdx.x;
    double result = 0.0;
    #pragma unroll
    for (int ch = 0; ch < NCH; ++ch) {
        const double h1 = (double)gh[ch * NBINS + t];
        const double h2 = (double)gh[(NCH + ch) * NBINS + t];
        const double s  = block_reduce256(sqrt(h1 * h2), sh4);
        const double s1 = block_reduce256(h1, sh4);
        const double s2 = block_reduce256(h2, sh4);
        const double denom = sqrt((s1 / (double)NBINS) * (s2 / (double)NBINS)) * (double)NBINS;
        const double v = 1.0 - s / denom;
        result += sqrt(v > 0.0 ? v : 0.0);
    }
    if (t == 0) out[0] = (float)result;
}

extern "C" void kernel_launch(void* const* d_in, const int* in_sizes, int n_in,
                              void* d_out, int out_size, void* d_ws, size_t ws_size,
                              hipStream_t stream) {
    const float* input = (const float*)d_in[0];
    const float* label = (const float*)d_in[1];
    float* out = (float*)d_out;
    unsigned int* gh = (unsigned int*)d_ws;

    // d_ws is poisoned with 0xAA before every timed launch — zero the hists.
    hipMemsetAsync(gh, 0, NHIST * sizeof(unsigned int), stream);

    hist_atomic<<<NCH * BLOCKS_PER_JOB, THREADS, 0, stream>>>(input, gh);
    hist_rmw   <<<NCH * BLOCKS_PER_JOB, THREADS, 0, stream>>>(label, gh);
    bhat_kernel<<<1, 256, 0, stream>>>(gh, out);
}